// Round 6
// baseline (436.829 us; speedup 1.0000x reference)
//
#include <hip/hip_runtime.h>

#define TPB 256
#define BK_SHIFT 7
#define BK_SIZE 128
#define NBK_MAX 784     // >= ceil(100000/128)=782
#define CAP 2816        // per-bucket region capacity (mean 2046, +17 sigma)
#define SC_EPB 8192     // edges per scatter block (196 scatter blocks)
#define TILE_BATCH 2    // gemm1 tiles grabbed per wave per atomic

typedef __attribute__((ext_vector_type(8))) short bf16x8;
typedef __attribute__((ext_vector_type(4))) float f32x4;
typedef __attribute__((ext_vector_type(2))) float f32x2;
typedef __attribute__((ext_vector_type(4))) unsigned short u16x4;

__device__ __forceinline__ unsigned short f2bf(float f) {
    unsigned u = __float_as_uint(f);
    unsigned r = (u + 0x7FFFu + ((u >> 16) & 1u)) >> 16;   // RNE
    return (unsigned short)r;
}
__device__ __forceinline__ float bf2f(unsigned short b) {
    return __uint_as_float((unsigned)b << 16);
}
__device__ __forceinline__ void acc4(f32x4& a, u16x4 v) {
    a.x += bf2f(v.x); a.y += bf2f(v.y); a.z += bf2f(v.z); a.w += bf2f(v.w);
}

// Hand-rolled grid barrier. Requires all blocks co-resident:
// grid=782 <= 4 blocks/CU (from __launch_bounds__(256,4)) * 256 CUs = 1024.
// Release/acquire via __threadfence() (agent scope: L2 writeback+inv on
// gfx950), arrive/poll via device-scope atomics. bar zeroed per launch.
__device__ __forceinline__ void grid_barrier(int* bar, int nblk) {
    __syncthreads();
    if (threadIdx.x == 0) {
        __threadfence();                     // release my writes
        atomicAdd(bar, 1);
        while (atomicAdd(bar, 0) < nblk)
            __builtin_amdgcn_s_sleep(2);
        __threadfence();                     // acquire others' writes
    }
    __syncthreads();
}

// =======================================================================
// ONE kernel, 3 stages separated by grid_barrier():
//   stage0: blocks [0,NSC) bin-scatter edges into fixed-CAP bucket regions
//           (gfill pre-zeroed by memset); then ALL blocks pull gemm1 tiles
//           from a global counter (y1=x@W1l bf16, c1=x@W1r+b1).
//   stage1: block b = bucket b: in-LDS counting sort + gather1 + relu +
//           gemm2 -> y2b(bf16), c2.
//   stage2: block b = bucket b: re-sort + gather2 + final fc -> out.
// Shared memory is a 12.8KB union reused across stages.
// =======================================================================
__global__ __launch_bounds__(256, 4) void fused_all(
    const int* __restrict__ src, const int* __restrict__ dst,
    int* __restrict__ gfill, int* __restrict__ tcur, int* __restrict__ bar,
    int* __restrict__ pk,
    int E, int NBK, int NSC,
    const float* __restrict__ A,      // x [N][128]
    const float* __restrict__ W1l, const float* __restrict__ W1r,
    const float* __restrict__ b1,
    unsigned short* __restrict__ y1b, // [N][32] bf16
    float* __restrict__ c1,           // [N][32]
    const float* __restrict__ W2l, const float* __restrict__ W2r,
    const float* __restrict__ b2,
    unsigned short* __restrict__ y2b, // [N][16] bf16
    float* __restrict__ c2,           // [N][16]
    const float* __restrict__ Wfc, const float* __restrict__ bfc,
    float* __restrict__ out, int N)
{
    __shared__ int smem[3200];        // 12.8 KB union

    const int t    = threadIdx.x;
    const int bid  = blockIdx.x;
    const int lane = t & 63;

    // ---------------- stage 0a: bin scatter (blocks [0,NSC)) -------------
    if (bid < NSC) {
        int* lcnt  = smem;            // [784]
        int* lbase = smem + 784;      // [784]
        int* lrank = smem + 1568;     // [784]
        const int e0 = bid * SC_EPB;

        for (int i = t; i < NBK; i += 256) { lcnt[i] = 0; lrank[i] = 0; }
        __syncthreads();

        // phase 1: count (int4, coalesced; E%4==0)
        #pragma unroll
        for (int k = 0; k < SC_EPB / 1024; ++k) {
            int e = e0 + k * 1024 + t * 4;
            if (e < E) {
                int4 d = *(const int4*)&dst[e];
                atomicAdd(&lcnt[d.x >> BK_SHIFT], 1);
                atomicAdd(&lcnt[d.y >> BK_SHIFT], 1);
                atomicAdd(&lcnt[d.z >> BK_SHIFT], 1);
                atomicAdd(&lcnt[d.w >> BK_SHIFT], 1);
            }
        }
        __syncthreads();

        // phase 2: reserve per-bucket ranges (gfill pre-zeroed by memset)
        for (int i = t; i < NBK; i += 256) {
            int c = lcnt[i];
            if (c) lbase[i] = atomicAdd(&gfill[i], c);
        }
        __syncthreads();

        // phase 3: scatter (dst re-read is L2-hot from phase 1)
        #pragma unroll
        for (int k = 0; k < SC_EPB / 1024; ++k) {
            int e = e0 + k * 1024 + t * 4;
            if (e < E) {
                int4 d = *(const int4*)&dst[e];
                int4 s = *(const int4*)&src[e];
                {
                    int bb = d.x >> BK_SHIFT;
                    int pos = lbase[bb] + atomicAdd(&lrank[bb], 1);
                    if (pos < CAP) pk[(size_t)bb * CAP + pos] =
                        (s.x << BK_SHIFT) | (d.x & (BK_SIZE - 1));
                }
                {
                    int bb = d.y >> BK_SHIFT;
                    int pos = lbase[bb] + atomicAdd(&lrank[bb], 1);
                    if (pos < CAP) pk[(size_t)bb * CAP + pos] =
                        (s.y << BK_SHIFT) | (d.y & (BK_SIZE - 1));
                }
                {
                    int bb = d.z >> BK_SHIFT;
                    int pos = lbase[bb] + atomicAdd(&lrank[bb], 1);
                    if (pos < CAP) pk[(size_t)bb * CAP + pos] =
                        (s.z << BK_SHIFT) | (d.z & (BK_SIZE - 1));
                }
                {
                    int bb = d.w >> BK_SHIFT;
                    int pos = lbase[bb] + atomicAdd(&lrank[bb], 1);
                    if (pos < CAP) pk[(size_t)bb * CAP + pos] =
                        (s.w << BK_SHIFT) | (d.w & (BK_SIZE - 1));
                }
            }
        }
    }

    // ---------------- stage 0b: gemm1, dynamic tile pull -----------------
    {
        const int m    = lane & 15;
        const int quad = lane >> 4;
        const int ntiles = (N + 15) >> 4;

        bf16x8 Bf[4][4];   // [kc][jt]; jt 0,1 -> W1l; jt 2,3 -> W1r
        #pragma unroll
        for (int kc = 0; kc < 4; ++kc) {
            #pragma unroll
            for (int jt = 0; jt < 4; ++jt) {
                const float* W = (jt < 2) ? W1l : W1r;
                const int col = (jt & 1) * 16 + m;
                #pragma unroll
                for (int j = 0; j < 8; ++j) {
                    int k = kc * 32 + quad * 8 + j;
                    Bf[kc][jt][j] = (short)f2bf(W[k * 32 + col]);
                }
            }
        }

        const float bias0 = b1[m];
        const float bias1 = b1[16 + m];

        for (;;) {
            int t0 = 0;
            if (lane == 0) t0 = atomicAdd(tcur, TILE_BATCH);
            t0 = __shfl(t0, 0, 64);
            if (t0 >= ntiles) break;

            for (int it = 0; it < TILE_BATCH; ++it) {
                const int tile = t0 + it;
                if (tile >= ntiles) break;
                const int node0 = tile * 16;
                const int gn = node0 + m;
                const bool okA = gn < N;
                const float* rowp = A + (size_t)gn * 128;

                bf16x8 Af[4];
                #pragma unroll
                for (int kc = 0; kc < 4; ++kc) {
                    f32x4 v0 = {0.f, 0.f, 0.f, 0.f};
                    f32x4 v1 = {0.f, 0.f, 0.f, 0.f};
                    if (okA) {
                        v0 = __builtin_nontemporal_load((const f32x4*)&rowp[kc * 32 + quad * 8]);
                        v1 = __builtin_nontemporal_load((const f32x4*)&rowp[kc * 32 + quad * 8 + 4]);
                    }
                    Af[kc][0] = (short)f2bf(v0.x); Af[kc][1] = (short)f2bf(v0.y);
                    Af[kc][2] = (short)f2bf(v0.z); Af[kc][3] = (short)f2bf(v0.w);
                    Af[kc][4] = (short)f2bf(v1.x); Af[kc][5] = (short)f2bf(v1.y);
                    Af[kc][6] = (short)f2bf(v1.z); Af[kc][7] = (short)f2bf(v1.w);
                }

                f32x4 acc[4] = {{0.f,0.f,0.f,0.f},{0.f,0.f,0.f,0.f},
                                {0.f,0.f,0.f,0.f},{0.f,0.f,0.f,0.f}};
                #pragma unroll
                for (int kc = 0; kc < 4; ++kc) {
                    #pragma unroll
                    for (int jt = 0; jt < 4; ++jt)
                        acc[jt] = __builtin_amdgcn_mfma_f32_16x16x32_bf16(
                            Af[kc], Bf[kc][jt], acc[jt], 0, 0, 0);
                }

                const int nodeBase = node0 + quad * 4;
                #pragma unroll
                for (int reg = 0; reg < 4; ++reg) {
                    const int node = nodeBase + reg;
                    if (node < N) {
                        y1b[(size_t)node * 32 + m]      = f2bf(acc[0][reg]);
                        y1b[(size_t)node * 32 + 16 + m] = f2bf(acc[1][reg]);
                        c1 [(size_t)node * 32 + m]      = acc[2][reg] + bias0;
                        c1 [(size_t)node * 32 + 16 + m] = acc[3][reg] + bias1;
                    }
                }
            }
        }
    }

    grid_barrier(&bar[0], NBK);   // pk, y1b, c1 complete

    // ---------------- stage 1: sort + gather1 + relu + gemm2 -------------
    {
        int* lcnt = smem;            // [128]
        int* soff = smem + 128;      // [128] inclusive scan
        int* wcur = smem + 256;      // [128]
        int* sidx = smem + 384;      // [CAP]

        const int b = bid;
        const size_t base = (size_t)b * CAP;
        const int cnt  = min(gfill[b], CAP);
        const int node0 = b * BK_SIZE;

        if (t < BK_SIZE) lcnt[t] = 0;
        __syncthreads();

        for (int j = t; j < cnt; j += 256)
            atomicAdd(&lcnt[pk[base + j] & (BK_SIZE - 1)], 1);
        __syncthreads();

        int v = (t < BK_SIZE) ? lcnt[t] : 0;
        if (t < BK_SIZE) soff[t] = v;
        __syncthreads();
        for (int off = 1; off < BK_SIZE; off <<= 1) {
            int u = (t < BK_SIZE && t >= off) ? soff[t - off] : 0;
            __syncthreads();
            if (t < BK_SIZE) soff[t] += u;
            __syncthreads();
        }
        if (t < BK_SIZE) wcur[t] = soff[t] - v;
        __syncthreads();

        for (int j = t; j < cnt; j += 256) {
            int pv = pk[base + j];
            int d  = pv & (BK_SIZE - 1);
            int pos = atomicAdd(&wcur[d], 1);
            sidx[pos] = pv >> BK_SHIFT;
        }
        __syncthreads();

        // per-node walk: 8 lanes/node, 32 nodes per pass, 4 passes
        const int q = t & 7;
        #pragma unroll
        for (int pass = 0; pass < 4; ++pass) {
            const int nl = pass * 32 + (t >> 3);
            const int node = node0 + nl;
            const bool active = node < N;
            float h[4] = {0.f, 0.f, 0.f, 0.f};
            if (active) {
                const int deg = lcnt[nl];
                const int en  = soff[nl];
                const int st  = en - deg;
                const float w = 1.0f / fmaxf((float)deg, 1.0f);

                f32x4 a0 = {0.f,0.f,0.f,0.f};
                f32x4 a1 = {0.f,0.f,0.f,0.f};
                f32x4 a2 = {0.f,0.f,0.f,0.f};
                f32x4 a3 = {0.f,0.f,0.f,0.f};
                int j = st;
                for (; j + 3 < en; j += 4) {
                    int s0 = sidx[j], s1 = sidx[j+1], s2 = sidx[j+2], s3 = sidx[j+3];
                    u16x4 v0 = *(const u16x4*)&y1b[(size_t)s0 * 32 + q * 4];
                    u16x4 v1 = *(const u16x4*)&y1b[(size_t)s1 * 32 + q * 4];
                    u16x4 v2 = *(const u16x4*)&y1b[(size_t)s2 * 32 + q * 4];
                    u16x4 v3 = *(const u16x4*)&y1b[(size_t)s3 * 32 + q * 4];
                    acc4(a0, v0); acc4(a1, v1); acc4(a2, v2); acc4(a3, v3);
                }
                for (; j < en; ++j) {
                    u16x4 vv = *(const u16x4*)&y1b[(size_t)sidx[j] * 32 + q * 4];
                    acc4(a0, vv);
                }
                f32x4 acc;
                acc.x = (a0.x + a1.x) + (a2.x + a3.x);
                acc.y = (a0.y + a1.y) + (a2.y + a3.y);
                acc.z = (a0.z + a1.z) + (a2.z + a3.z);
                acc.w = (a0.w + a1.w) + (a2.w + a3.w);

                f32x4 c = *(const f32x4*)&c1[(size_t)node * 32 + q * 4];
                h[0] = fmaxf(c.x + acc.x * w, 0.f);
                h[1] = fmaxf(c.y + acc.y * w, 0.f);
                h[2] = fmaxf(c.z + acc.z * w, 0.f);
                h[3] = fmaxf(c.w + acc.w * w, 0.f);
            }

            // gemm2 across the 8-lane group
            const int  j0  = q * 4;
            const bool isY = (j0 < 16);
            const int  jj  = isY ? j0 : (j0 - 16);
            const float* Wb = isY ? W2l : W2r;

            float o0 = 0.f, o1 = 0.f, o2 = 0.f, o3 = 0.f;
            #pragma unroll
            for (int k = 0; k < 32; ++k) {
                float hk = __shfl(h[k & 3], k >> 2, 8);
                f32x4 wv = *(const f32x4*)&Wb[k * 16 + jj];
                o0 += hk * wv.x; o1 += hk * wv.y; o2 += hk * wv.z; o3 += hk * wv.w;
            }

            if (active) {
                if (isY) {
                    u16x4 r;
                    r.x = f2bf(o0); r.y = f2bf(o1); r.z = f2bf(o2); r.w = f2bf(o3);
                    *(u16x4*)&y2b[(size_t)node * 16 + jj] = r;
                } else {
                    f32x4 bb = *(const f32x4*)&b2[jj];
                    f32x4 ov = {o0 + bb.x, o1 + bb.y, o2 + bb.z, o3 + bb.w};
                    *(f32x4*)&c2[(size_t)node * 16 + jj] = ov;  // stays L2-hot for stage 2
                }
            }
        }
    }

    grid_barrier(&bar[16], NBK);   // y2b, c2 complete

    // ---------------- stage 2: sort + gather2 + final fc -----------------
    {
        int* lcnt = smem;
        int* soff = smem + 128;
        int* wcur = smem + 256;
        int* sidx = smem + 384;

        const int b = bid;
        const size_t base = (size_t)b * CAP;
        const int cnt  = min(gfill[b], CAP);
        const int node0 = b * BK_SIZE;

        if (t < BK_SIZE) lcnt[t] = 0;
        __syncthreads();

        for (int j = t; j < cnt; j += 256)
            atomicAdd(&lcnt[pk[base + j] & (BK_SIZE - 1)], 1);
        __syncthreads();

        int v = (t < BK_SIZE) ? lcnt[t] : 0;
        if (t < BK_SIZE) soff[t] = v;
        __syncthreads();
        for (int off = 1; off < BK_SIZE; off <<= 1) {
            int u = (t < BK_SIZE && t >= off) ? soff[t - off] : 0;
            __syncthreads();
            if (t < BK_SIZE) soff[t] += u;
            __syncthreads();
        }
        if (t < BK_SIZE) wcur[t] = soff[t] - v;
        __syncthreads();

        for (int j = t; j < cnt; j += 256) {
            int pv = pk[base + j];
            int d  = pv & (BK_SIZE - 1);
            int pos = atomicAdd(&wcur[d], 1);
            sidx[pos] = pv >> BK_SHIFT;
        }
        __syncthreads();

        // per-node walk: 4 lanes/node, 64 nodes per pass, 2 passes
        const int q = t & 3;
        #pragma unroll
        for (int pass = 0; pass < 2; ++pass) {
            const int nl = pass * 64 + (t >> 2);
            const int node = node0 + nl;
            if (node < N) {
                const int deg = lcnt[nl];
                const int en  = soff[nl];
                const int st  = en - deg;
                const float w = 1.0f / fmaxf((float)deg, 1.0f);

                f32x4 a0 = {0.f,0.f,0.f,0.f};
                f32x4 a1 = {0.f,0.f,0.f,0.f};
                f32x4 a2 = {0.f,0.f,0.f,0.f};
                f32x4 a3 = {0.f,0.f,0.f,0.f};
                int j = st;
                for (; j + 3 < en; j += 4) {
                    int s0 = sidx[j], s1 = sidx[j+1], s2 = sidx[j+2], s3 = sidx[j+3];
                    u16x4 v0 = *(const u16x4*)&y2b[(size_t)s0 * 16 + q * 4];
                    u16x4 v1 = *(const u16x4*)&y2b[(size_t)s1 * 16 + q * 4];
                    u16x4 v2 = *(const u16x4*)&y2b[(size_t)s2 * 16 + q * 4];
                    u16x4 v3 = *(const u16x4*)&y2b[(size_t)s3 * 16 + q * 4];
                    acc4(a0, v0); acc4(a1, v1); acc4(a2, v2); acc4(a3, v3);
                }
                for (; j < en; ++j) {
                    u16x4 vv = *(const u16x4*)&y2b[(size_t)sidx[j] * 16 + q * 4];
                    acc4(a0, vv);
                }
                f32x4 acc;
                acc.x = (a0.x + a1.x) + (a2.x + a3.x);
                acc.y = (a0.y + a1.y) + (a2.y + a3.y);
                acc.z = (a0.z + a1.z) + (a2.z + a3.z);
                acc.w = (a0.w + a1.w) + (a2.w + a3.w);

                f32x4 c = *(const f32x4*)&c2[(size_t)node * 16 + q * 4];
                float h0 = fmaxf(c.x + acc.x * w, 0.f);
                float h1 = fmaxf(c.y + acc.y * w, 0.f);
                float h2 = fmaxf(c.z + acc.z * w, 0.f);
                float h3 = fmaxf(c.w + acc.w * w, 0.f);

                const float* Wq = &Wfc[q * 8];
                float o0 = h0 * Wq[0] + h1 * Wq[2] + h2 * Wq[4] + h3 * Wq[6];
                float o1 = h0 * Wq[1] + h1 * Wq[3] + h2 * Wq[5] + h3 * Wq[7];

                o0 += __shfl_xor(o0, 1); o0 += __shfl_xor(o0, 2);
                o1 += __shfl_xor(o1, 1); o1 += __shfl_xor(o1, 2);

                if (q == 0) {
                    f32x2 ov = {o0 + bfc[0], o1 + bfc[1]};
                    __builtin_nontemporal_store(ov, (f32x2*)&out[(size_t)node * 2]);
                }
            } else {
                // keep shuffles convergent within the wave (no-op values)
                float z = 0.f;
                z += __shfl_xor(z, 1); z += __shfl_xor(z, 2);
            }
        }
    }
}

extern "C" void kernel_launch(void* const* d_in, const int* in_sizes, int n_in,
                              void* d_out, int out_size, void* d_ws, size_t ws_size,
                              hipStream_t stream)
{
    const float* x   = (const float*)d_in[0];
    const int*   ei  = (const int*)d_in[1];   // int32 (JAX default)
    const float* W1l = (const float*)d_in[2];
    const float* b1  = (const float*)d_in[3];
    const float* W1r = (const float*)d_in[4];
    const float* W2l = (const float*)d_in[5];
    const float* b2  = (const float*)d_in[6];
    const float* W2r = (const float*)d_in[7];
    const float* Wfc = (const float*)d_in[8];
    const float* bfc = (const float*)d_in[9];
    float* out = (float*)d_out;

    int N = in_sizes[0] / 128;
    int E = in_sizes[1] / 2;
    const int* src = ei;
    const int* dst = ei + E;

    int NBK = (N + BK_SIZE - 1) / BK_SIZE;   // 782
    int NSC = (E + SC_EPB - 1) / SC_EPB;     // 196

    int*   gfill = (int*)d_ws;                      // NBK_MAX
    int*   tcur  = gfill + NBK_MAX;                 // 16 (1 used)
    int*   bar   = tcur + 16;                       // 32 (2 used, line-split)
    int*   pk    = bar + 32;                        // NBK_MAX * CAP
    unsigned short* y1b = (unsigned short*)(pk + (size_t)NBK_MAX * CAP); // N*32 bf16
    float* c1          = (float*)(y1b + (size_t)N * 32);    // N*32 f32
    unsigned short* y2b = (unsigned short*)(c1 + (size_t)N * 32); // N*16 bf16
    float* c2          = (float*)(y2b + (size_t)N * 16);    // N*16 f32

    // zero bucket-fill counters + gemm tile cursor + barrier cells
    hipMemsetAsync(gfill, 0, (size_t)(NBK_MAX + 48) * sizeof(int), stream);

    fused_all<<<NBK, TPB, 0, stream>>>(
        src, dst, gfill, tcur, bar, pk, E, NBK, NSC,
        x, W1l, W1r, b1, y1b, c1,
        W2l, W2r, b2, y2b, c2,
        Wfc, bfc, out, N);
}

// Round 7
// 285.970 us; speedup vs baseline: 1.5275x; 1.5275x over previous
//
#include <hip/hip_runtime.h>

#define TPB 256
#define BK_SHIFT 7
#define BK_SIZE 128
#define NBK_MAX 784     // >= ceil(100000/128)=782
#define CAP 2816        // per-bucket region capacity (mean 2046, +17 sigma)
#define SC_EPB 4096     // edges per scatter block (391 scatter blocks)
#define GRID_BUILD 1568
#define TILE_BATCH 2    // gemm1 tiles grabbed per wave per atomic

typedef __attribute__((ext_vector_type(8))) short bf16x8;
typedef __attribute__((ext_vector_type(4))) float f32x4;
typedef __attribute__((ext_vector_type(2))) float f32x2;
typedef __attribute__((ext_vector_type(4))) unsigned short u16x4;

__device__ __forceinline__ unsigned short f2bf(float f) {
    unsigned u = __float_as_uint(f);
    unsigned r = (u + 0x7FFFu + ((u >> 16) & 1u)) >> 16;   // RNE
    return (unsigned short)r;
}
__device__ __forceinline__ float bf2f(unsigned short b) {
    return __uint_as_float((unsigned)b << 16);
}
__device__ __forceinline__ void acc4(f32x4& a, u16x4 v) {
    a.x += bf2f(v.x); a.y += bf2f(v.y); a.z += bf2f(v.z); a.w += bf2f(v.w);
}

// ===== fused: edge bin-scatter (blocks [0,NSC)) + gemm1 (all blocks) ======
// Scatter: fixed-CAP bucket regions, per-block LDS count + one global
// atomicAdd per (block,bucket). Scatter blocks FALL THROUGH into the
// dynamic gemm1 tile pull (no return) so the tail self-balances.
// Gemm1: y1lo/y1hi (bf16, channel-split) = x@W1l, c1 = x@W1r + b1.
__global__ __launch_bounds__(256) void build_and_gemm1(
    const int* __restrict__ src, const int* __restrict__ dst,
    int* __restrict__ gfill, int* __restrict__ tcur, int* __restrict__ pk,
    int E, int NBK, int NSC,
    const float* __restrict__ A,      // x [N][128]
    const float* __restrict__ Wl,     // [128][32]
    const float* __restrict__ Wr,     // [128][32]
    const float* __restrict__ b,      // [32]
    unsigned short* __restrict__ y1lo, // [N][16] bf16 ch 0-15
    unsigned short* __restrict__ y1hi, // [N][16] bf16 ch 16-31
    float* __restrict__ C,            // c1 [N][32]
    int N)
{
    __shared__ int lcnt[NBK_MAX];
    __shared__ int lbase[NBK_MAX];
    __shared__ int lrank[NBK_MAX];

    const int t = threadIdx.x;

    if ((int)blockIdx.x < NSC) {
        // -------------------- scatter part --------------------
        const int e0 = blockIdx.x * SC_EPB;

        for (int i = t; i < NBK; i += 256) { lcnt[i] = 0; lrank[i] = 0; }
        __syncthreads();

        // phase 1: count (int4, coalesced; E%4==0)
        #pragma unroll
        for (int k = 0; k < SC_EPB / 1024; ++k) {
            int e = e0 + k * 1024 + t * 4;
            if (e < E) {
                int4 d = *(const int4*)&dst[e];
                atomicAdd(&lcnt[d.x >> BK_SHIFT], 1);
                atomicAdd(&lcnt[d.y >> BK_SHIFT], 1);
                atomicAdd(&lcnt[d.z >> BK_SHIFT], 1);
                atomicAdd(&lcnt[d.w >> BK_SHIFT], 1);
            }
        }
        __syncthreads();

        // phase 2: reserve per-bucket ranges (gfill pre-zeroed by memset)
        for (int i = t; i < NBK; i += 256) {
            int c = lcnt[i];
            if (c) lbase[i] = atomicAdd(&gfill[i], c);
        }
        __syncthreads();

        // phase 3: scatter (dst re-read is L2-hot from phase 1)
        #pragma unroll
        for (int k = 0; k < SC_EPB / 1024; ++k) {
            int e = e0 + k * 1024 + t * 4;
            if (e < E) {
                int4 d = *(const int4*)&dst[e];
                int4 s = *(const int4*)&src[e];
                {
                    int bb = d.x >> BK_SHIFT;
                    int pos = lbase[bb] + atomicAdd(&lrank[bb], 1);
                    if (pos < CAP) pk[(size_t)bb * CAP + pos] =
                        (s.x << BK_SHIFT) | (d.x & (BK_SIZE - 1));
                }
                {
                    int bb = d.y >> BK_SHIFT;
                    int pos = lbase[bb] + atomicAdd(&lrank[bb], 1);
                    if (pos < CAP) pk[(size_t)bb * CAP + pos] =
                        (s.y << BK_SHIFT) | (d.y & (BK_SIZE - 1));
                }
                {
                    int bb = d.z >> BK_SHIFT;
                    int pos = lbase[bb] + atomicAdd(&lrank[bb], 1);
                    if (pos < CAP) pk[(size_t)bb * CAP + pos] =
                        (s.z << BK_SHIFT) | (d.z & (BK_SIZE - 1));
                }
                {
                    int bb = d.w >> BK_SHIFT;
                    int pos = lbase[bb] + atomicAdd(&lrank[bb], 1);
                    if (pos < CAP) pk[(size_t)bb * CAP + pos] =
                        (s.w << BK_SHIFT) | (d.w & (BK_SIZE - 1));
                }
            }
        }
        // fall through into gemm1 tile pull
    }

    // -------------------- gemm1: dynamic tile pull --------------------
    {
        const int lane = t & 63;
        const int m    = lane & 15;
        const int quad = lane >> 4;
        const int ntiles = (N + 15) >> 4;

        bf16x8 Bf[4][4];   // [kc][jt]; jt 0,1 -> Wl; jt 2,3 -> Wr
        #pragma unroll
        for (int kc = 0; kc < 4; ++kc) {
            #pragma unroll
            for (int jt = 0; jt < 4; ++jt) {
                const float* W = (jt < 2) ? Wl : Wr;
                const int col = (jt & 1) * 16 + m;
                #pragma unroll
                for (int j = 0; j < 8; ++j) {
                    int k = kc * 32 + quad * 8 + j;
                    Bf[kc][jt][j] = (short)f2bf(W[k * 32 + col]);
                }
            }
        }

        const float bias0 = b[m];
        const float bias1 = b[16 + m];

        for (;;) {
            int t0 = 0;
            if (lane == 0) t0 = atomicAdd(tcur, TILE_BATCH);
            t0 = __shfl(t0, 0, 64);
            if (t0 >= ntiles) break;

            for (int it = 0; it < TILE_BATCH; ++it) {
                const int tile = t0 + it;
                if (tile >= ntiles) break;
                const int node0 = tile * 16;
                const int gn = node0 + m;
                const bool okA = gn < N;
                const float* rowp = A + (size_t)gn * 128;

                bf16x8 Af[4];
                #pragma unroll
                for (int kc = 0; kc < 4; ++kc) {
                    f32x4 v0 = {0.f, 0.f, 0.f, 0.f};
                    f32x4 v1 = {0.f, 0.f, 0.f, 0.f};
                    if (okA) {
                        v0 = __builtin_nontemporal_load((const f32x4*)&rowp[kc * 32 + quad * 8]);
                        v1 = __builtin_nontemporal_load((const f32x4*)&rowp[kc * 32 + quad * 8 + 4]);
                    }
                    Af[kc][0] = (short)f2bf(v0.x); Af[kc][1] = (short)f2bf(v0.y);
                    Af[kc][2] = (short)f2bf(v0.z); Af[kc][3] = (short)f2bf(v0.w);
                    Af[kc][4] = (short)f2bf(v1.x); Af[kc][5] = (short)f2bf(v1.y);
                    Af[kc][6] = (short)f2bf(v1.z); Af[kc][7] = (short)f2bf(v1.w);
                }

                f32x4 acc[4] = {{0.f,0.f,0.f,0.f},{0.f,0.f,0.f,0.f},
                                {0.f,0.f,0.f,0.f},{0.f,0.f,0.f,0.f}};
                #pragma unroll
                for (int kc = 0; kc < 4; ++kc) {
                    #pragma unroll
                    for (int jt = 0; jt < 4; ++jt)
                        acc[jt] = __builtin_amdgcn_mfma_f32_16x16x32_bf16(
                            Af[kc], Bf[kc][jt], acc[jt], 0, 0, 0);
                }

                const int nodeBase = node0 + quad * 4;
                #pragma unroll
                for (int reg = 0; reg < 4; ++reg) {
                    const int node = nodeBase + reg;
                    if (node < N) {
                        y1lo[(size_t)node * 16 + m] = f2bf(acc[0][reg]);
                        y1hi[(size_t)node * 16 + m] = f2bf(acc[1][reg]);
                        C [(size_t)node * 32 + m]      = acc[2][reg] + bias0;
                        C [(size_t)node * 32 + 16 + m] = acc[3][reg] + bias1;
                    }
                }
            }
        }
    }
}

// ------- gather1+relu+gemm2, in-LDS counting sort, channel-split gather ---
// Block b = bucket b (128 nodes). Gather runs in TWO temporal passes:
// pass A over y1lo (3.2MB, L2-fits), pass B over y1hi. Within each pass
// lanes q and q+4 split the edge list (even/odd) for the same 4-channel
// slice; one shfl_xor(4) combines.
__global__ __launch_bounds__(256) void gather_gemm2(
    const int* __restrict__ gfill, const int* __restrict__ pk,
    const unsigned short* __restrict__ y1lo, // [N][16]
    const unsigned short* __restrict__ y1hi, // [N][16]
    const float* __restrict__ c1,            // [N][32]
    const float* __restrict__ W2l, const float* __restrict__ W2r,
    const float* __restrict__ b2,
    unsigned short* __restrict__ y2b, float* __restrict__ c2, int N)
{
    __shared__ int lcnt[BK_SIZE];
    __shared__ int soff[BK_SIZE];   // inclusive scan
    __shared__ int wcur[BK_SIZE];
    __shared__ int sidx[CAP];

    const int t = threadIdx.x;
    const int b = blockIdx.x;
    const size_t base = (size_t)b * CAP;
    const int cnt  = min(gfill[b], CAP);
    const int node0 = b * BK_SIZE;

    if (t < BK_SIZE) lcnt[t] = 0;
    __syncthreads();

    for (int j = t; j < cnt; j += 256)
        atomicAdd(&lcnt[pk[base + j] & (BK_SIZE - 1)], 1);
    __syncthreads();

    int v = (t < BK_SIZE) ? lcnt[t] : 0;
    if (t < BK_SIZE) soff[t] = v;
    __syncthreads();
    for (int off = 1; off < BK_SIZE; off <<= 1) {
        int u = (t < BK_SIZE && t >= off) ? soff[t - off] : 0;
        __syncthreads();
        if (t < BK_SIZE) soff[t] += u;
        __syncthreads();
    }
    if (t < BK_SIZE) wcur[t] = soff[t] - v;
    __syncthreads();

    for (int j = t; j < cnt; j += 256) {
        int pv = pk[base + j];
        int d  = pv & (BK_SIZE - 1);
        int pos = atomicAdd(&wcur[d], 1);
        sidx[pos] = pv >> BK_SHIFT;
    }
    __syncthreads();

    // per-node walk: 8 lanes/node, 32 nodes per pass, 4 passes
    const int q    = t & 7;
    const int qq   = q & 3;
    const int half = (q >> 2) & 1;
    #pragma unroll
    for (int pass = 0; pass < 4; ++pass) {
        const int nl = pass * 32 + (t >> 3);
        const int node = node0 + nl;
        const bool active = node < N;
        float h[4] = {0.f, 0.f, 0.f, 0.f};
        if (active) {
            const int deg = lcnt[nl];
            const int en  = soff[nl];
            const int st  = en - deg;
            const float w = 1.0f / fmaxf((float)deg, 1.0f);

            // ---- pass A: lo channels (y1lo), lanes split edges even/odd
            f32x4 a0 = {0.f,0.f,0.f,0.f};
            f32x4 a1 = {0.f,0.f,0.f,0.f};
            f32x4 a2 = {0.f,0.f,0.f,0.f};
            f32x4 a3 = {0.f,0.f,0.f,0.f};
            int j = st + half;
            for (; j + 6 < en; j += 8) {
                int s0 = sidx[j], s1 = sidx[j+2], s2 = sidx[j+4], s3 = sidx[j+6];
                acc4(a0, *(const u16x4*)&y1lo[(size_t)s0 * 16 + qq * 4]);
                acc4(a1, *(const u16x4*)&y1lo[(size_t)s1 * 16 + qq * 4]);
                acc4(a2, *(const u16x4*)&y1lo[(size_t)s2 * 16 + qq * 4]);
                acc4(a3, *(const u16x4*)&y1lo[(size_t)s3 * 16 + qq * 4]);
            }
            for (; j < en; j += 2)
                acc4(a0, *(const u16x4*)&y1lo[(size_t)sidx[j] * 16 + qq * 4]);
            f32x4 fa;
            fa.x = (a0.x + a1.x) + (a2.x + a3.x);
            fa.y = (a0.y + a1.y) + (a2.y + a3.y);
            fa.z = (a0.z + a1.z) + (a2.z + a3.z);
            fa.w = (a0.w + a1.w) + (a2.w + a3.w);
            fa.x += __shfl_xor(fa.x, 4, 8);
            fa.y += __shfl_xor(fa.y, 4, 8);
            fa.z += __shfl_xor(fa.z, 4, 8);
            fa.w += __shfl_xor(fa.w, 4, 8);

            // ---- pass B: hi channels (y1hi)
            a0 = (f32x4){0.f,0.f,0.f,0.f};
            a1 = (f32x4){0.f,0.f,0.f,0.f};
            a2 = (f32x4){0.f,0.f,0.f,0.f};
            a3 = (f32x4){0.f,0.f,0.f,0.f};
            j = st + half;
            for (; j + 6 < en; j += 8) {
                int s0 = sidx[j], s1 = sidx[j+2], s2 = sidx[j+4], s3 = sidx[j+6];
                acc4(a0, *(const u16x4*)&y1hi[(size_t)s0 * 16 + qq * 4]);
                acc4(a1, *(const u16x4*)&y1hi[(size_t)s1 * 16 + qq * 4]);
                acc4(a2, *(const u16x4*)&y1hi[(size_t)s2 * 16 + qq * 4]);
                acc4(a3, *(const u16x4*)&y1hi[(size_t)s3 * 16 + qq * 4]);
            }
            for (; j < en; j += 2)
                acc4(a0, *(const u16x4*)&y1hi[(size_t)sidx[j] * 16 + qq * 4]);
            f32x4 fb;
            fb.x = (a0.x + a1.x) + (a2.x + a3.x);
            fb.y = (a0.y + a1.y) + (a2.y + a3.y);
            fb.z = (a0.z + a1.z) + (a2.z + a3.z);
            fb.w = (a0.w + a1.w) + (a2.w + a3.w);
            fb.x += __shfl_xor(fb.x, 4, 8);
            fb.y += __shfl_xor(fb.y, 4, 8);
            fb.z += __shfl_xor(fb.z, 4, 8);
            fb.w += __shfl_xor(fb.w, 4, 8);

            // thread q owns channels [q*4, q*4+4): q<4 -> lo, q>=4 -> hi
            f32x4 acc = (q < 4) ? fa : fb;

            f32x4 c = *(const f32x4*)&c1[(size_t)node * 32 + q * 4];
            h[0] = fmaxf(c.x + acc.x * w, 0.f);
            h[1] = fmaxf(c.y + acc.y * w, 0.f);
            h[2] = fmaxf(c.z + acc.z * w, 0.f);
            h[3] = fmaxf(c.w + acc.w * w, 0.f);
        }

        // gemm2 across the 8-lane group
        const int  j0  = q * 4;
        const bool isY = (j0 < 16);
        const int  jj  = isY ? j0 : (j0 - 16);
        const float* Wb = isY ? W2l : W2r;

        float o0 = 0.f, o1 = 0.f, o2 = 0.f, o3 = 0.f;
        #pragma unroll
        for (int k = 0; k < 32; ++k) {
            float hk = __shfl(h[k & 3], k >> 2, 8);
            f32x4 wv = *(const f32x4*)&Wb[k * 16 + jj];
            o0 += hk * wv.x; o1 += hk * wv.y; o2 += hk * wv.z; o3 += hk * wv.w;
        }

        if (active) {
            if (isY) {
                u16x4 r;
                r.x = f2bf(o0); r.y = f2bf(o1); r.z = f2bf(o2); r.w = f2bf(o3);
                *(u16x4*)&y2b[(size_t)node * 16 + jj] = r;
            } else {
                f32x4 bb = *(const f32x4*)&b2[jj];
                f32x4 ov = {o0 + bb.x, o1 + bb.y, o2 + bb.z, o3 + bb.w};
                *(f32x4*)&c2[(size_t)node * 16 + jj] = ov;
            }
        }
    }
}

// ------- gather2+final, fused in-LDS counting sort ------------------------
__global__ __launch_bounds__(256) void gather_final(
    const int* __restrict__ gfill, const int* __restrict__ pk,
    const unsigned short* __restrict__ Yb,  // y2 bf16 [N][16]
    const float* __restrict__ c2,           // [N][16]
    const float* __restrict__ Wfc,          // [16][2]
    const float* __restrict__ bfc,          // [2]
    float* __restrict__ out, int N)
{
    __shared__ int lcnt[BK_SIZE];
    __shared__ int soff[BK_SIZE];
    __shared__ int wcur[BK_SIZE];
    __shared__ int sidx[CAP];

    const int t = threadIdx.x;
    const int b = blockIdx.x;
    const size_t base = (size_t)b * CAP;
    const int cnt  = min(gfill[b], CAP);
    const int node0 = b * BK_SIZE;

    if (t < BK_SIZE) lcnt[t] = 0;
    __syncthreads();

    for (int j = t; j < cnt; j += 256)
        atomicAdd(&lcnt[pk[base + j] & (BK_SIZE - 1)], 1);
    __syncthreads();

    int v = (t < BK_SIZE) ? lcnt[t] : 0;
    if (t < BK_SIZE) soff[t] = v;
    __syncthreads();
    for (int off = 1; off < BK_SIZE; off <<= 1) {
        int u = (t < BK_SIZE && t >= off) ? soff[t - off] : 0;
        __syncthreads();
        if (t < BK_SIZE) soff[t] += u;
        __syncthreads();
    }
    if (t < BK_SIZE) wcur[t] = soff[t] - v;
    __syncthreads();

    for (int j = t; j < cnt; j += 256) {
        int pv = pk[base + j];
        int d  = pv & (BK_SIZE - 1);
        int pos = atomicAdd(&wcur[d], 1);
        sidx[pos] = pv >> BK_SHIFT;
    }
    __syncthreads();

    // per-node walk: 4 lanes/node, 64 nodes per pass, 2 passes
    const int q = t & 3;
    #pragma unroll
    for (int pass = 0; pass < 2; ++pass) {
        const int nl = pass * 64 + (t >> 2);
        const int node = node0 + nl;
        if (node < N) {
            const int deg = lcnt[nl];
            const int en  = soff[nl];
            const int st  = en - deg;
            const float w = 1.0f / fmaxf((float)deg, 1.0f);

            f32x4 a0 = {0.f,0.f,0.f,0.f};
            f32x4 a1 = {0.f,0.f,0.f,0.f};
            f32x4 a2 = {0.f,0.f,0.f,0.f};
            f32x4 a3 = {0.f,0.f,0.f,0.f};
            int j = st;
            for (; j + 3 < en; j += 4) {
                int s0 = sidx[j], s1 = sidx[j+1], s2 = sidx[j+2], s3 = sidx[j+3];
                acc4(a0, *(const u16x4*)&Yb[(size_t)s0 * 16 + q * 4]);
                acc4(a1, *(const u16x4*)&Yb[(size_t)s1 * 16 + q * 4]);
                acc4(a2, *(const u16x4*)&Yb[(size_t)s2 * 16 + q * 4]);
                acc4(a3, *(const u16x4*)&Yb[(size_t)s3 * 16 + q * 4]);
            }
            for (; j < en; ++j)
                acc4(a0, *(const u16x4*)&Yb[(size_t)sidx[j] * 16 + q * 4]);
            f32x4 acc;
            acc.x = (a0.x + a1.x) + (a2.x + a3.x);
            acc.y = (a0.y + a1.y) + (a2.y + a3.y);
            acc.z = (a0.z + a1.z) + (a2.z + a3.z);
            acc.w = (a0.w + a1.w) + (a2.w + a3.w);

            f32x4 c = *(const f32x4*)&c2[(size_t)node * 16 + q * 4];
            float h0 = fmaxf(c.x + acc.x * w, 0.f);
            float h1 = fmaxf(c.y + acc.y * w, 0.f);
            float h2 = fmaxf(c.z + acc.z * w, 0.f);
            float h3 = fmaxf(c.w + acc.w * w, 0.f);

            const float* Wq = &Wfc[q * 8];
            float o0 = h0 * Wq[0] + h1 * Wq[2] + h2 * Wq[4] + h3 * Wq[6];
            float o1 = h0 * Wq[1] + h1 * Wq[3] + h2 * Wq[5] + h3 * Wq[7];

            o0 += __shfl_xor(o0, 1); o0 += __shfl_xor(o0, 2);
            o1 += __shfl_xor(o1, 1); o1 += __shfl_xor(o1, 2);

            if (q == 0) {
                f32x2 ov = {o0 + bfc[0], o1 + bfc[1]};
                __builtin_nontemporal_store(ov, (f32x2*)&out[(size_t)node * 2]);
            }
        } else {
            // keep shuffles convergent within the wave (no-op values)
            float z = 0.f;
            z += __shfl_xor(z, 1); z += __shfl_xor(z, 2);
        }
    }
}

extern "C" void kernel_launch(void* const* d_in, const int* in_sizes, int n_in,
                              void* d_out, int out_size, void* d_ws, size_t ws_size,
                              hipStream_t stream)
{
    const float* x   = (const float*)d_in[0];
    const int*   ei  = (const int*)d_in[1];   // int32 (JAX default)
    const float* W1l = (const float*)d_in[2];
    const float* b1  = (const float*)d_in[3];
    const float* W1r = (const float*)d_in[4];
    const float* W2l = (const float*)d_in[5];
    const float* b2  = (const float*)d_in[6];
    const float* W2r = (const float*)d_in[7];
    const float* Wfc = (const float*)d_in[8];
    const float* bfc = (const float*)d_in[9];
    float* out = (float*)d_out;

    const int N = in_sizes[0] / 128;
    const int E = in_sizes[1] / 2;
    const int* src = ei;
    const int* dst = ei + E;

    const int NBK = (N + BK_SIZE - 1) / BK_SIZE;   // 782
    const int NSC = (E + SC_EPB - 1) / SC_EPB;     // 391

    int*   gfill = (int*)d_ws;                      // NBK_MAX
    int*   tcur  = gfill + NBK_MAX;                 // 16 (1 used)
    int*   pk    = tcur + 16;                       // NBK_MAX * CAP
    unsigned short* y1lo = (unsigned short*)(pk + (size_t)NBK_MAX * CAP); // N*16 bf16
    unsigned short* y1hi = y1lo + (size_t)N * 16;                         // N*16 bf16
    float* c1           = (float*)(y1hi + (size_t)N * 16);   // N*32 f32
    unsigned short* y2b = (unsigned short*)(c1 + (size_t)N * 32); // N*16 bf16
    float* c2           = (float*)(y2b + (size_t)N * 16);    // N*16 f32

    // zero bucket-fill counters + gemm tile cursor
    hipMemsetAsync(gfill, 0, (size_t)(NBK_MAX + 16) * sizeof(int), stream);

    // ---- fused: bucketed edge build + layer-1 GEMM (overlapped) ----
    build_and_gemm1<<<GRID_BUILD, TPB, 0, stream>>>(
        src, dst, gfill, tcur, pk, E, NBK, NSC,
        x, W1l, W1r, b1, y1lo, y1hi, c1, N);

    // ---- fused sort + gather1 + relu + gemm2 (channel-split) ----
    gather_gemm2<<<NBK, TPB, 0, stream>>>(
        gfill, pk, y1lo, y1hi, c1, W2l, W2r, b2, y2b, c2, N);

    // ---- fused sort + gather2 + final ----
    gather_final<<<NBK, TPB, 0, stream>>>(
        gfill, pk, y2b, c2, Wfc, bfc, out, N);
}

// Round 8
// 191.409 us; speedup vs baseline: 2.2822x; 1.4940x over previous
//
#include <hip/hip_runtime.h>

#define TPB 256
#define BK_SHIFT 7
#define BK_SIZE 128
#define NBK_MAX 784     // >= ceil(100000/128)=782
#define CAP 2816        // per-bucket region capacity (mean 2046, +17 sigma)
#define SC_EPB 8192     // edges per scatter block (196 scatter blocks)
#define GEMM_BLKS 1024

typedef __attribute__((ext_vector_type(8))) short bf16x8;
typedef __attribute__((ext_vector_type(4))) float f32x4;
typedef __attribute__((ext_vector_type(2))) float f32x2;
typedef __attribute__((ext_vector_type(4))) unsigned short u16x4;

__device__ __forceinline__ unsigned short f2bf(float f) {
    unsigned u = __float_as_uint(f);
    unsigned r = (u + 0x7FFFu + ((u >> 16) & 1u)) >> 16;   // RNE
    return (unsigned short)r;
}
__device__ __forceinline__ float bf2f(unsigned short b) {
    return __uint_as_float((unsigned)b << 16);
}
__device__ __forceinline__ void acc4(f32x4& a, u16x4 v) {
    a.x += bf2f(v.x); a.y += bf2f(v.y); a.z += bf2f(v.z); a.w += bf2f(v.w);
}

// ===== fused: edge bin-scatter (blocks [0,NSC)) + gemm1 (the rest) ========
// Scatter: per-block LDS counting sort of its 8192 edges by bucket, then
// COALESCED write-out (consecutive sorted indices -> consecutive global
// addresses within each bucket fragment). One global atomicAdd per
// (block,bucket) reserves the fragment. Scatter blocks return early.
// Gemm1: y1(bf16)=x@W1l, c1=x@W1r+b1 via MFMA, static-stride tiles.
__global__ __launch_bounds__(256) void build_and_gemm1(
    const int* __restrict__ src, const int* __restrict__ dst,
    int* __restrict__ gfill, int* __restrict__ pk, int E, int NBK, int NSC,
    const float* __restrict__ A,      // x [N][128]
    const float* __restrict__ Wl,     // [128][32]
    const float* __restrict__ Wr,     // [128][32]
    const float* __restrict__ b,      // [32]
    unsigned short* __restrict__ Yb,  // y1 bf16 [N][32]
    float* __restrict__ C,            // c1 [N][32]
    int N)
{
    __shared__ int lcnt [NBK_MAX];
    __shared__ int soff [1024];       // inclusive scan (padded to 1024)
    __shared__ int lbase[NBK_MAX];
    __shared__ int lrank[NBK_MAX];
    __shared__ int spv  [SC_EPB];     // bucket-sorted packed edges
    __shared__ unsigned short sbk[SC_EPB]; // bucket id per sorted slot

    const int t = threadIdx.x;

    if ((int)blockIdx.x < NSC) {
        // -------------------- scatter part --------------------
        const int e0 = blockIdx.x * SC_EPB;

        for (int i = t; i < NBK_MAX; i += 256) { lcnt[i] = 0; lrank[i] = 0; }
        __syncthreads();

        // phase 1: histogram (int4, coalesced; E%4==0 so int4 all-or-nothing)
        #pragma unroll
        for (int k = 0; k < SC_EPB / 1024; ++k) {
            int e = e0 + k * 1024 + t * 4;
            if (e < E) {
                int4 d = *(const int4*)&dst[e];
                atomicAdd(&lcnt[d.x >> BK_SHIFT], 1);
                atomicAdd(&lcnt[d.y >> BK_SHIFT], 1);
                atomicAdd(&lcnt[d.z >> BK_SHIFT], 1);
                atomicAdd(&lcnt[d.w >> BK_SHIFT], 1);
            }
        }
        __syncthreads();

        // phase 2a: inclusive scan over 1024 padded slots (4 elems/thread)
        for (int i = t; i < 1024; i += 256) soff[i] = (i < NBK) ? lcnt[i] : 0;
        __syncthreads();
        for (int off = 1; off < 1024; off <<= 1) {
            int u0 = (t       >= off) ? soff[t       - off] : 0;
            int u1 = (t + 256 >= off) ? soff[t + 256 - off] : 0;
            int u2 = (t + 512 >= off) ? soff[t + 512 - off] : 0;
            int u3 = (t + 768 >= off) ? soff[t + 768 - off] : 0;
            __syncthreads();
            soff[t] += u0; soff[t + 256] += u1;
            soff[t + 512] += u2; soff[t + 768] += u3;
            __syncthreads();
        }

        // phase 2b: reserve global fragments (gfill pre-zeroed by memset)
        for (int i = t; i < NBK; i += 256) {
            int c = lcnt[i];
            if (c) lbase[i] = atomicAdd(&gfill[i], c);
        }
        __syncthreads();

        // phase 3: LDS scatter into bucket-sorted order (dst/src L2-hot)
        #pragma unroll
        for (int k = 0; k < SC_EPB / 1024; ++k) {
            int e = e0 + k * 1024 + t * 4;
            if (e < E) {
                int4 d = *(const int4*)&dst[e];
                int4 s = *(const int4*)&src[e];
                {
                    int bb = d.x >> BK_SHIFT;
                    int pos = (soff[bb] - lcnt[bb]) + atomicAdd(&lrank[bb], 1);
                    spv[pos] = (s.x << BK_SHIFT) | (d.x & (BK_SIZE - 1));
                    sbk[pos] = (unsigned short)bb;
                }
                {
                    int bb = d.y >> BK_SHIFT;
                    int pos = (soff[bb] - lcnt[bb]) + atomicAdd(&lrank[bb], 1);
                    spv[pos] = (s.y << BK_SHIFT) | (d.y & (BK_SIZE - 1));
                    sbk[pos] = (unsigned short)bb;
                }
                {
                    int bb = d.z >> BK_SHIFT;
                    int pos = (soff[bb] - lcnt[bb]) + atomicAdd(&lrank[bb], 1);
                    spv[pos] = (s.z << BK_SHIFT) | (d.z & (BK_SIZE - 1));
                    sbk[pos] = (unsigned short)bb;
                }
                {
                    int bb = d.w >> BK_SHIFT;
                    int pos = (soff[bb] - lcnt[bb]) + atomicAdd(&lrank[bb], 1);
                    spv[pos] = (s.w << BK_SHIFT) | (d.w & (BK_SIZE - 1));
                    sbk[pos] = (unsigned short)bb;
                }
            }
        }
        __syncthreads();

        // phase 4: coalesced write-out (runs of consecutive addresses)
        const int blockcnt = soff[NBK - 1];
        for (int i = t; i < blockcnt; i += 256) {
            int bb = sbk[i];
            int gpos = lbase[bb] + (i - (soff[bb] - lcnt[bb]));
            if (gpos < CAP) pk[(size_t)bb * CAP + gpos] = spv[i];
        }
        return;
    }

    // -------------------- gemm1 part (static stride) --------------------
    const int lane = t & 63;
    const int m    = lane & 15;
    const int quad = lane >> 4;
    const int wave   = (blockIdx.x - NSC) * (blockDim.x >> 6) + (t >> 6);
    const int nwaves = GEMM_BLKS * (blockDim.x >> 6);
    const int ntiles = (N + 15) >> 4;

    bf16x8 Bf[4][4];   // [kc][jt]; jt 0,1 -> Wl; jt 2,3 -> Wr
    #pragma unroll
    for (int kc = 0; kc < 4; ++kc) {
        #pragma unroll
        for (int jt = 0; jt < 4; ++jt) {
            const float* W = (jt < 2) ? Wl : Wr;
            const int col = (jt & 1) * 16 + m;
            #pragma unroll
            for (int j = 0; j < 8; ++j) {
                int k = kc * 32 + quad * 8 + j;
                Bf[kc][jt][j] = (short)f2bf(W[k * 32 + col]);
            }
        }
    }

    const float bias0 = b[m];
    const float bias1 = b[16 + m];

    for (int tile = wave; tile < ntiles; tile += nwaves) {
        const int node0 = tile * 16;
        const int gn = node0 + m;
        const bool okA = gn < N;
        const float* rowp = A + (size_t)gn * 128;

        bf16x8 Af[4];
        #pragma unroll
        for (int kc = 0; kc < 4; ++kc) {
            f32x4 v0 = {0.f, 0.f, 0.f, 0.f};
            f32x4 v1 = {0.f, 0.f, 0.f, 0.f};
            if (okA) {
                v0 = __builtin_nontemporal_load((const f32x4*)&rowp[kc * 32 + quad * 8]);
                v1 = __builtin_nontemporal_load((const f32x4*)&rowp[kc * 32 + quad * 8 + 4]);
            }
            Af[kc][0] = (short)f2bf(v0.x); Af[kc][1] = (short)f2bf(v0.y);
            Af[kc][2] = (short)f2bf(v0.z); Af[kc][3] = (short)f2bf(v0.w);
            Af[kc][4] = (short)f2bf(v1.x); Af[kc][5] = (short)f2bf(v1.y);
            Af[kc][6] = (short)f2bf(v1.z); Af[kc][7] = (short)f2bf(v1.w);
        }

        f32x4 acc[4] = {{0.f,0.f,0.f,0.f},{0.f,0.f,0.f,0.f},
                        {0.f,0.f,0.f,0.f},{0.f,0.f,0.f,0.f}};
        #pragma unroll
        for (int kc = 0; kc < 4; ++kc) {
            #pragma unroll
            for (int jt = 0; jt < 4; ++jt)
                acc[jt] = __builtin_amdgcn_mfma_f32_16x16x32_bf16(
                    Af[kc], Bf[kc][jt], acc[jt], 0, 0, 0);
        }

        const int nodeBase = node0 + quad * 4;
        #pragma unroll
        for (int reg = 0; reg < 4; ++reg) {
            const int node = nodeBase + reg;
            if (node < N) {
                Yb[(size_t)node * 32 + m]      = f2bf(acc[0][reg]);
                Yb[(size_t)node * 32 + 16 + m] = f2bf(acc[1][reg]);
                C [(size_t)node * 32 + m]      = acc[2][reg] + bias0;
                C [(size_t)node * 32 + 16 + m] = acc[3][reg] + bias1;
            }
        }
    }
}

// ------- gather1+relu+gemm2, fused in-LDS counting sort -------------------
// Block b = bucket b (128 nodes): sort pk slice into sidx[], then per-node
// walk (8 lanes/node, unroll-4) gathering y1b rows.
__global__ __launch_bounds__(256) void gather_gemm2(
    const int* __restrict__ gfill, const int* __restrict__ pk,
    const unsigned short* __restrict__ Yb,  // y1 bf16 [N][32]
    const float* __restrict__ c1,           // [N][32]
    const float* __restrict__ W2l, const float* __restrict__ W2r,
    const float* __restrict__ b2,
    unsigned short* __restrict__ y2b, float* __restrict__ c2, int N)
{
    __shared__ int lcnt[BK_SIZE];
    __shared__ int soff[BK_SIZE];   // inclusive scan
    __shared__ int wcur[BK_SIZE];
    __shared__ int sidx[CAP];

    const int t = threadIdx.x;
    const int b = blockIdx.x;
    const size_t base = (size_t)b * CAP;
    const int cnt  = min(gfill[b], CAP);
    const int node0 = b * BK_SIZE;

    if (t < BK_SIZE) lcnt[t] = 0;
    __syncthreads();

    for (int j = t; j < cnt; j += 256)
        atomicAdd(&lcnt[pk[base + j] & (BK_SIZE - 1)], 1);
    __syncthreads();

    int v = (t < BK_SIZE) ? lcnt[t] : 0;
    if (t < BK_SIZE) soff[t] = v;
    __syncthreads();
    for (int off = 1; off < BK_SIZE; off <<= 1) {
        int u = (t < BK_SIZE && t >= off) ? soff[t - off] : 0;
        __syncthreads();
        if (t < BK_SIZE) soff[t] += u;
        __syncthreads();
    }
    if (t < BK_SIZE) wcur[t] = soff[t] - v;
    __syncthreads();

    for (int j = t; j < cnt; j += 256) {
        int pv = pk[base + j];
        int d  = pv & (BK_SIZE - 1);
        int pos = atomicAdd(&wcur[d], 1);
        sidx[pos] = pv >> BK_SHIFT;
    }
    __syncthreads();

    // per-node walk: 8 lanes/node, 32 nodes per pass, 4 passes
    const int q = t & 7;
    #pragma unroll
    for (int pass = 0; pass < 4; ++pass) {
        const int nl = pass * 32 + (t >> 3);
        const int node = node0 + nl;
        const bool active = node < N;
        float h[4] = {0.f, 0.f, 0.f, 0.f};
        if (active) {
            const int deg = lcnt[nl];
            const int en  = soff[nl];
            const int st  = en - deg;
            const float w = 1.0f / fmaxf((float)deg, 1.0f);

            f32x4 a0 = {0.f,0.f,0.f,0.f};
            f32x4 a1 = {0.f,0.f,0.f,0.f};
            f32x4 a2 = {0.f,0.f,0.f,0.f};
            f32x4 a3 = {0.f,0.f,0.f,0.f};
            int j = st;
            for (; j + 3 < en; j += 4) {
                int s0 = sidx[j], s1 = sidx[j+1], s2 = sidx[j+2], s3 = sidx[j+3];
                u16x4 v0 = *(const u16x4*)&Yb[(size_t)s0 * 32 + q * 4];
                u16x4 v1 = *(const u16x4*)&Yb[(size_t)s1 * 32 + q * 4];
                u16x4 v2 = *(const u16x4*)&Yb[(size_t)s2 * 32 + q * 4];
                u16x4 v3 = *(const u16x4*)&Yb[(size_t)s3 * 32 + q * 4];
                acc4(a0, v0); acc4(a1, v1); acc4(a2, v2); acc4(a3, v3);
            }
            for (; j < en; ++j) {
                u16x4 vv = *(const u16x4*)&Yb[(size_t)sidx[j] * 32 + q * 4];
                acc4(a0, vv);
            }
            f32x4 acc;
            acc.x = (a0.x + a1.x) + (a2.x + a3.x);
            acc.y = (a0.y + a1.y) + (a2.y + a3.y);
            acc.z = (a0.z + a1.z) + (a2.z + a3.z);
            acc.w = (a0.w + a1.w) + (a2.w + a3.w);

            f32x4 c = __builtin_nontemporal_load((const f32x4*)&c1[(size_t)node * 32 + q * 4]);
            h[0] = fmaxf(c.x + acc.x * w, 0.f);
            h[1] = fmaxf(c.y + acc.y * w, 0.f);
            h[2] = fmaxf(c.z + acc.z * w, 0.f);
            h[3] = fmaxf(c.w + acc.w * w, 0.f);
        }

        // gemm2 across the 8-lane group
        const int  j0  = q * 4;
        const bool isY = (j0 < 16);
        const int  jj  = isY ? j0 : (j0 - 16);
        const float* Wb = isY ? W2l : W2r;

        float o0 = 0.f, o1 = 0.f, o2 = 0.f, o3 = 0.f;
        #pragma unroll
        for (int k = 0; k < 32; ++k) {
            float hk = __shfl(h[k & 3], k >> 2, 8);
            f32x4 wv = *(const f32x4*)&Wb[k * 16 + jj];
            o0 += hk * wv.x; o1 += hk * wv.y; o2 += hk * wv.z; o3 += hk * wv.w;
        }

        if (active) {
            if (isY) {
                u16x4 r;
                r.x = f2bf(o0); r.y = f2bf(o1); r.z = f2bf(o2); r.w = f2bf(o3);
                *(u16x4*)&y2b[(size_t)node * 16 + jj] = r;     // keep in L2 for gf
            } else {
                f32x4 bb = *(const f32x4*)&b2[jj];
                f32x4 ov = {o0 + bb.x, o1 + bb.y, o2 + bb.z, o3 + bb.w};
                __builtin_nontemporal_store(ov, (f32x4*)&c2[(size_t)node * 16 + jj]);
            }
        }
    }
}

// ------- gather2+final, fused in-LDS counting sort ------------------------
__global__ __launch_bounds__(256) void gather_final(
    const int* __restrict__ gfill, const int* __restrict__ pk,
    const unsigned short* __restrict__ Yb,  // y2 bf16 [N][16]
    const float* __restrict__ c2,           // [N][16]
    const float* __restrict__ Wfc,          // [16][2]
    const float* __restrict__ bfc,          // [2]
    float* __restrict__ out, int N)
{
    __shared__ int lcnt[BK_SIZE];
    __shared__ int soff[BK_SIZE];
    __shared__ int wcur[BK_SIZE];
    __shared__ int sidx[CAP];

    const int t = threadIdx.x;
    const int b = blockIdx.x;
    const size_t base = (size_t)b * CAP;
    const int cnt  = min(gfill[b], CAP);
    const int node0 = b * BK_SIZE;

    if (t < BK_SIZE) lcnt[t] = 0;
    __syncthreads();

    for (int j = t; j < cnt; j += 256)
        atomicAdd(&lcnt[pk[base + j] & (BK_SIZE - 1)], 1);
    __syncthreads();

    int v = (t < BK_SIZE) ? lcnt[t] : 0;
    if (t < BK_SIZE) soff[t] = v;
    __syncthreads();
    for (int off = 1; off < BK_SIZE; off <<= 1) {
        int u = (t < BK_SIZE && t >= off) ? soff[t - off] : 0;
        __syncthreads();
        if (t < BK_SIZE) soff[t] += u;
        __syncthreads();
    }
    if (t < BK_SIZE) wcur[t] = soff[t] - v;
    __syncthreads();

    for (int j = t; j < cnt; j += 256) {
        int pv = pk[base + j];
        int d  = pv & (BK_SIZE - 1);
        int pos = atomicAdd(&wcur[d], 1);
        sidx[pos] = pv >> BK_SHIFT;
    }
    __syncthreads();

    // per-node walk: 4 lanes/node, 64 nodes per pass, 2 passes
    const int q = t & 3;
    #pragma unroll
    for (int pass = 0; pass < 2; ++pass) {
        const int nl = pass * 64 + (t >> 2);
        const int node = node0 + nl;
        if (node < N) {
            const int deg = lcnt[nl];
            const int en  = soff[nl];
            const int st  = en - deg;
            const float w = 1.0f / fmaxf((float)deg, 1.0f);

            f32x4 a0 = {0.f,0.f,0.f,0.f};
            f32x4 a1 = {0.f,0.f,0.f,0.f};
            f32x4 a2 = {0.f,0.f,0.f,0.f};
            f32x4 a3 = {0.f,0.f,0.f,0.f};
            int j = st;
            for (; j + 3 < en; j += 4) {
                int s0 = sidx[j], s1 = sidx[j+1], s2 = sidx[j+2], s3 = sidx[j+3];
                acc4(a0, *(const u16x4*)&Yb[(size_t)s0 * 16 + q * 4]);
                acc4(a1, *(const u16x4*)&Yb[(size_t)s1 * 16 + q * 4]);
                acc4(a2, *(const u16x4*)&Yb[(size_t)s2 * 16 + q * 4]);
                acc4(a3, *(const u16x4*)&Yb[(size_t)s3 * 16 + q * 4]);
            }
            for (; j < en; ++j)
                acc4(a0, *(const u16x4*)&Yb[(size_t)sidx[j] * 16 + q * 4]);
            f32x4 acc;
            acc.x = (a0.x + a1.x) + (a2.x + a3.x);
            acc.y = (a0.y + a1.y) + (a2.y + a3.y);
            acc.z = (a0.z + a1.z) + (a2.z + a3.z);
            acc.w = (a0.w + a1.w) + (a2.w + a3.w);

            f32x4 c = __builtin_nontemporal_load((const f32x4*)&c2[(size_t)node * 16 + q * 4]);
            float h0 = fmaxf(c.x + acc.x * w, 0.f);
            float h1 = fmaxf(c.y + acc.y * w, 0.f);
            float h2 = fmaxf(c.z + acc.z * w, 0.f);
            float h3 = fmaxf(c.w + acc.w * w, 0.f);

            const float* Wq = &Wfc[q * 8];
            float o0 = h0 * Wq[0] + h1 * Wq[2] + h2 * Wq[4] + h3 * Wq[6];
            float o1 = h0 * Wq[1] + h1 * Wq[3] + h2 * Wq[5] + h3 * Wq[7];

            o0 += __shfl_xor(o0, 1); o0 += __shfl_xor(o0, 2);
            o1 += __shfl_xor(o1, 1); o1 += __shfl_xor(o1, 2);

            if (q == 0) {
                f32x2 ov = {o0 + bfc[0], o1 + bfc[1]};
                __builtin_nontemporal_store(ov, (f32x2*)&out[(size_t)node * 2]);
            }
        } else {
            // keep shuffles convergent within the wave (no-op values)
            float z = 0.f;
            z += __shfl_xor(z, 1); z += __shfl_xor(z, 2);
        }
    }
}

extern "C" void kernel_launch(void* const* d_in, const int* in_sizes, int n_in,
                              void* d_out, int out_size, void* d_ws, size_t ws_size,
                              hipStream_t stream)
{
    const float* x   = (const float*)d_in[0];
    const int*   ei  = (const int*)d_in[1];   // int32 (JAX default)
    const float* W1l = (const float*)d_in[2];
    const float* b1  = (const float*)d_in[3];
    const float* W1r = (const float*)d_in[4];
    const float* W2l = (const float*)d_in[5];
    const float* b2  = (const float*)d_in[6];
    const float* W2r = (const float*)d_in[7];
    const float* Wfc = (const float*)d_in[8];
    const float* bfc = (const float*)d_in[9];
    float* out = (float*)d_out;

    const int N = in_sizes[0] / 128;
    const int E = in_sizes[1] / 2;
    const int* src = ei;
    const int* dst = ei + E;

    const int NBK = (N + BK_SIZE - 1) / BK_SIZE;   // 782
    const int NSC = (E + SC_EPB - 1) / SC_EPB;     // 196

    int*   gfill = (int*)d_ws;                      // NBK_MAX
    int*   pk    = gfill + NBK_MAX + 16;            // NBK_MAX * CAP
    unsigned short* y1b = (unsigned short*)(pk + (size_t)NBK_MAX * CAP); // N*32 bf16
    float* c1          = (float*)(y1b + (size_t)N * 32);    // N*32 f32
    unsigned short* y2b = (unsigned short*)(c1 + (size_t)N * 32); // N*16 bf16
    float* c2          = (float*)(y2b + (size_t)N * 16);    // N*16 f32

    // zero bucket-fill counters
    hipMemsetAsync(gfill, 0, (size_t)(NBK_MAX + 16) * sizeof(int), stream);

    // ---- fused: bucketed edge build (LDS-sorted, coalesced) + gemm1 ----
    build_and_gemm1<<<NSC + GEMM_BLKS, TPB, 0, stream>>>(
        src, dst, gfill, pk, E, NBK, NSC,
        x, W1l, W1r, b1, y1b, c1, N);

    // ---- fused sort + gather1 + relu + gemm2 ----
    gather_gemm2<<<NBK, TPB, 0, stream>>>(
        gfill, pk, y1b, c1, W2l, W2r, b2, y2b, c2, N);

    // ---- fused sort + gather2 + final ----
    gather_final<<<NBK, TPB, 0, stream>>>(
        gfill, pk, y2b, c2, Wfc, bfc, out, N);
}